// Round 13
// baseline (408.344 us; speedup 1.0000x reference)
//
#include <hip/hip_runtime.h>

typedef __attribute__((ext_vector_type(4))) float  f32x4;
typedef __attribute__((ext_vector_type(4))) float  float4v;
typedef __attribute__((ext_vector_type(4))) short  short4v;
typedef __attribute__((ext_vector_type(8))) short  short8v;
typedef __attribute__((ext_vector_type(2))) unsigned uint2v;
typedef __attribute__((ext_vector_type(8))) __bf16 bf16x8;

union Frag { short4v h[2]; short8v s8; unsigned u[4]; };
union BF4  { uint2v u2; short4v s4; };

__device__ __forceinline__ short f2bf(float f) {
  unsigned u = __builtin_bit_cast(unsigned, f);
  u = (u + 0x7fffu + ((u >> 16) & 1u)) >> 16;
  return (short)u;
}

// HW packed f32->bf16 (RNE)
__device__ __forceinline__ unsigned cvt_pk_bf16(float a, float b) {
  unsigned r;
  asm("v_cvt_pk_bf16_f32 %0, %1, %2" : "=v"(r) : "v"(a), "v"(b));
  return r;
}
__device__ __forceinline__ short4v f4_to_bf4(float4v v) {
  BF4 r;
  r.u2 = uint2v{ cvt_pk_bf16(v[0], v[1]), cvt_pk_bf16(v[2], v[3]) };
  return r.s4;
}

__device__ __forceinline__ f32x4 mfma_bf16(const Frag& a, const Frag& b, f32x4 c) {
  return __builtin_amdgcn_mfma_f32_16x16x32_bf16(
      __builtin_bit_cast(bf16x8, a.s8), __builtin_bit_cast(bf16x8, b.s8), c, 0, 0, 0);
}

__device__ __forceinline__ int poscode(int i) {   // 11*(i/72) + (i/12)%6 + i%12
  int z = (i >= 72) ? 1 : 0;
  int rem = i - 72 * z;
  int y = rem / 12;
  return 11 * z + y + (rem - 12 * y);
}

// k-permute within a 32-chunk so one short8 at [lg*8] = MFMA operand order
__device__ __forceinline__ int kperm(int r) {
  return (r & 16) ? (((r - 16) >> 2) * 8 + 4 + (r & 3)) : ((r >> 2) * 8 + (r & 3));
}

// ---------------------------------------------------------------- K0: weights
// wtq [576][192] bf16 k-PERMUTED (proven r9-11); wto [192][192] bf16 PLAIN (r1-11)
__global__ __launch_bounds__(256) void k_transpose_w(
    const float* __restrict__ w_qkv, const float* __restrict__ w_o,
    short* __restrict__ wtq, short* __restrict__ wto) {
  int idx = blockIdx.x * 256 + threadIdx.x;
  if (idx < 110592) {
    int k = idx / 576, c = idx % 576;
    wtq[c * 192 + (k & ~31) + kperm(k & 31)] = f2bf(w_qkv[idx]);
  } else {
    int j = idx - 110592;
    int k = j / 192, c = j % 192;
    wto[c * 192 + k] = f2bf(w_o[j]);
  }
}

// ---------------------------------------------------------------- K0b: bias matrix
__global__ __launch_bounds__(256) void k_bias(
    const float* __restrict__ btab, float* __restrict__ bias6) {
  int idx = blockIdx.x * 256 + threadIdx.x;
  if (idx >= 124416) return;
  int h = idx / 20736, r = idx % 20736, m = r / 144, n = r % 144;
  bias6[idx] = btab[(poscode(m) - poscode(n) + 27) * 6 + h];
}

// ------------------------------------------- K1: fused QKV + attention (no oproj)
// One 576-thread block (9 waves) per window b; wave w owns rows w*16..w*16+15.
// A) x->regs  B) QKV GEMM, simple direct B loads (Q->regs, K/V->LDS)
// C) attention, O written fp32 to out (round-11 epilogue).
__global__ __launch_bounds__(576, 3) void k_fused(
    const float* __restrict__ x, const float* __restrict__ bqkv,
    const short* __restrict__ wtq, const float* __restrict__ mask,
    const float* __restrict__ bias6, float* __restrict__ out) {
  __shared__ short k_l[6][144][40];   // 69120 B, d-permuted rows
  __shared__ short vt[6][32][168];    // 64512 B, [d][n-permuted 160]

  const int tid = threadIdx.x;
  const int lane = tid & 63, wv = tid >> 6;     // wv = 0..8
  const int l15 = lane & 15, lg = lane >> 4;

  // swizzle: (b, b+512) adjacent -> same XCD L2 (shared mask window)
  const int did = blockIdx.x;
  const int vid = (did & 7) * 128 + (did >> 3);
  const int b = (vid >> 1) + (vid & 1) * 512;
  const int wm = vid >> 1;
  const int row = wv * 16 + l15;                // token row in window

  // ---------------- phase A: x fragments into registers (MFMA slot order)
  const float* xrow = &x[(size_t)(b * 144 + row) * 192];
  Frag ax[6];
#pragma unroll
  for (int kc = 0; kc < 6; ++kc) {
    float4v x0 = *(const float4v*)&xrow[kc * 32 + lg * 4];
    float4v x1 = *(const float4v*)&xrow[kc * 32 + 16 + lg * 4];
    ax[kc].h[0] = f4_to_bf4(x0);
    ax[kc].h[1] = f4_to_bf4(x1);
  }

  // zero V^T tail slots (n 144..159): 6*32*16 = 3072 shorts
#pragma unroll
  for (int i = 0; i < 6; ++i) {
    int flat = tid + 576 * i;
    if (flat < 3072) {
      int h = flat >> 9, r = flat & 511;
      int d = r >> 4, jj = r & 15;
      vt[h][d][128 + (jj >> 2) * 8 + 4 + (jj & 3)] = 0;
    }
  }

  // ---------------- phase B: QKV GEMM, 36 col-tiles, direct B loads (L2-hot)
  Frag aq[6];          // Q fragments (stay in registers)
  f32x4 qc0;
#pragma unroll
  for (int pt = 0; pt < 36; ++pt) {
    const int part = pt / 12, r12 = pt % 12, hl = r12 >> 1, cc = r12 & 1;
    const int c0 = part * 192 + hl * 32 + cc * 16;
    f32x4 acc = {0.f, 0.f, 0.f, 0.f};
#pragma unroll
    for (int kc = 0; kc < 6; ++kc) {
      Frag bw;
      bw.s8 = *(const short8v*)&wtq[(c0 + l15) * 192 + kc * 32 + lg * 8];
      acc = mfma_bf16(bw, ax[kc], acc);
    }
    float4v bias4 = *(const float4v*)&bqkv[c0 + lg * 4];
    if (part == 0) {                   // Q: keep in regs (pre-scaled)
      f32x4 t = (acc + bias4) * 0.17677669529663687f;
      if (cc == 0) qc0 = t;
      else { aq[hl].h[0] = f4_to_bf4(qc0); aq[hl].h[1] = f4_to_bf4(t); }
    } else if (part == 1) {            // K -> LDS, d-permuted
      short4v sv = f4_to_bf4(acc + bias4);
      int d0 = cc * 16 + lg * 4, q4 = d0 >> 2;
      int dd0 = (q4 < 4) ? q4 * 8 : (q4 - 4) * 8 + 4;
      *(short4v*)&k_l[hl][row][dd0] = sv;
    } else {                           // V -> LDS transposed, n-permuted
      short4v sv = f4_to_bf4(acc + bias4);
      int np = (row & ~31) + kperm(row & 31);
      int d0 = cc * 16 + lg * 4;
      vt[hl][d0 + 0][np] = sv[0];
      vt[hl][d0 + 1][np] = sv[1];
      vt[hl][d0 + 2][np] = sv[2];
      vt[hl][d0 + 3][np] = sv[3];
    }
  }
  __syncthreads();

  // ---------------- phase C: attention; O written fp32 (round-11 epilogue)
  const int q = row;
  const float* maskw = &mask[(size_t)wm * 20736 + (size_t)q * 144];
  f32x4 mrow[9];
#pragma unroll
  for (int cf = 0; cf < 9; ++cf)
    mrow[cf] = *(const float4v*)&maskw[cf * 16 + lg * 4];

#pragma unroll
  for (int hl = 0; hl < 6; ++hl) {
    f32x4 s[9];                        // s[cf][reg] = S[q][cf*16+lg*4+reg]
#pragma unroll
    for (int cf = 0; cf < 9; ++cf) {
      Frag bk;
      bk.s8 = *(const short8v*)&k_l[hl][cf * 16 + l15][lg * 8];
      s[cf] = mfma_bf16(bk, aq[hl], f32x4{0.f, 0.f, 0.f, 0.f});
    }
    const float* brow = &bias6[(size_t)(hl * 144 + q) * 144];
#pragma unroll
    for (int cf = 0; cf < 9; ++cf) {
      float4v bv = *(const float4v*)&brow[cf * 16 + lg * 4];
      s[cf] += mrow[cf] + bv;
    }

    float mx = s[0][0];
#pragma unroll
    for (int cf = 0; cf < 9; ++cf)
#pragma unroll
      for (int reg = 0; reg < 4; ++reg) mx = fmaxf(mx, s[cf][reg]);
    mx = fmaxf(mx, __shfl_xor(mx, 16, 64));
    mx = fmaxf(mx, __shfl_xor(mx, 32, 64));
    float sum = 0.f;
#pragma unroll
    for (int cf = 0; cf < 9; ++cf)
#pragma unroll
      for (int reg = 0; reg < 4; ++reg) {
        float e = __expf(s[cf][reg] - mx);
        s[cf][reg] = e;
        sum += e;
      }
    sum += __shfl_xor(sum, 16, 64);
    sum += __shfl_xor(sum, 32, 64);
    const float rinv = 1.0f / sum;

    f32x4 o0 = {0.f, 0.f, 0.f, 0.f}, o1 = {0.f, 0.f, 0.f, 0.f};
#pragma unroll
    for (int kc = 0; kc < 5; ++kc) {
      Frag p, b0, b1;
      p.u[0] = cvt_pk_bf16(s[2 * kc][0], s[2 * kc][1]);
      p.u[1] = cvt_pk_bf16(s[2 * kc][2], s[2 * kc][3]);
      if (kc < 4) {
        p.u[2] = cvt_pk_bf16(s[2 * kc + 1][0], s[2 * kc + 1][1]);
        p.u[3] = cvt_pk_bf16(s[2 * kc + 1][2], s[2 * kc + 1][3]);
      } else {
        p.u[2] = 0; p.u[3] = 0;        // n=144 tail (vt tail pre-zeroed)
      }
      b0.s8 = *(const short8v*)&vt[hl][l15][kc * 32 + lg * 8];
      b1.s8 = *(const short8v*)&vt[hl][16 + l15][kc * 32 + lg * 8];
      o0 = mfma_bf16(b0, p, o0);
      o1 = mfma_bf16(b1, p, o1);
    }
    o0 *= rinv;
    o1 *= rinv;
    const size_t base = (size_t)(b * 144 + q) * 192 + hl * 32;
    *(float4v*)&out[base + lg * 4]      = o0;
    *(float4v*)&out[base + 16 + lg * 4] = o1;
  }
}

// ---------------------------------------------------------------- K2: out proj
// Round-11 k_oproj VERBATIM (in-place on out, plain wto) — proven r3-r11.
__global__ __launch_bounds__(256, 2) void k_oproj(
    float* __restrict__ io, const float* __restrict__ bo,
    const short* __restrict__ wto) {
  __shared__ short a_lds[64][200];
  __shared__ short bT[192][40];
  const int tid = threadIdx.x;
  const int lane = tid & 63, wv = tid >> 6;
  const int l15 = lane & 15, lg = lane >> 4;
  const int row0 = blockIdx.x * 64;

#pragma unroll
  for (int i = 0; i < 12; ++i) {
    int flat = tid + 256 * i;
    int r = flat / 48, c4 = flat % 48;
    float4v xv = *(const float4v*)&io[(size_t)(row0 + r) * 192 + c4 * 4];
    *(short4v*)&a_lds[r][c4 * 4] = f4_to_bf4(xv);
  }

  f32x4 acc[12];
#pragma unroll
  for (int i = 0; i < 12; ++i) acc[i] = f32x4{0.f, 0.f, 0.f, 0.f};

  for (int kc = 0; kc < 6; ++kc) {
    __syncthreads();
#pragma unroll
    for (int i = 0; i < 6; ++i) {
      int flat = tid + 256 * i;             // 192 cols x 8 quads
      int c = flat >> 3, kk = (flat & 7) << 2;
      *(short4v*)&bT[c][kk] = *(const short4v*)&wto[c * 192 + kc * 32 + kk];
    }
    __syncthreads();
    Frag a;
    a.h[0] = *(const short4v*)&a_lds[wv * 16 + l15][kc * 32 + lg * 4];
    a.h[1] = *(const short4v*)&a_lds[wv * 16 + l15][kc * 32 + lg * 4 + 16];
#pragma unroll
    for (int cf = 0; cf < 12; ++cf) {
      Frag bw;
      bw.h[0] = *(const short4v*)&bT[cf * 16 + l15][lg * 4];
      bw.h[1] = *(const short4v*)&bT[cf * 16 + l15][lg * 4 + 16];
      acc[cf] = mfma_bf16(bw, a, acc[cf]);  // swapped
    }
  }

  const int g = row0 + wv * 16 + l15;
#pragma unroll
  for (int cf = 0; cf < 12; ++cf) {
    int c0 = cf * 16 + lg * 4;
    float4v bias4 = *(const float4v*)&bo[c0];
    *(float4v*)&io[(size_t)g * 192 + c0] = acc[cf] + bias4;
  }
}

extern "C" void kernel_launch(void* const* d_in, const int* in_sizes, int n_in,
                              void* d_out, int out_size, void* d_ws, size_t ws_size,
                              hipStream_t stream) {
  const float* x    = (const float*)d_in[0];
  const float* mask = (const float*)d_in[1];
  const float* wqkv = (const float*)d_in[2];
  const float* bqkv = (const float*)d_in[3];
  const float* wo   = (const float*)d_in[4];
  const float* bo   = (const float*)d_in[5];
  const float* btab = (const float*)d_in[6];
  float* out = (float*)d_out;

  short* wtq   = (short*)d_ws;               // 110,592 shorts (k-permuted)
  short* wto   = wtq + 110592;               //  36,864 shorts (PLAIN)
  float* bias6 = (float*)(wto + 36864);      // 124,416 floats (497 KB)

  k_transpose_w<<<576, 256, 0, stream>>>(wqkv, wo, wtq, wto);
  k_bias<<<486, 256, 0, stream>>>(btab, bias6);
  k_fused<<<1024, 576, 0, stream>>>(x, bqkv, wtq, mask, bias6, out);
  k_oproj<<<2304, 256, 0, stream>>>(out, bo, wto);
}